// Round 1
// baseline (519.501 us; speedup 1.0000x reference)
//
#include <hip/hip_runtime.h>
#include <math.h>

typedef __attribute__((ext_vector_type(8))) short bf16x8;
typedef __attribute__((ext_vector_type(4))) short short4v;
typedef __attribute__((ext_vector_type(4))) float f32x4;

constexpr int S   = 2048;
constexpr int HID = 2048;
constexpr int NH  = 16;
constexpr int HD  = 128;
constexpr int HALF = 64;

// scale constants, computed in double exactly as the Python reference does
#define SCORE_SCALE ((float)(0.06 * 0.06 * 0.08838834764831845))   // Q_ROT*K_ROT*INV_SQRT_HD
#define OSCALE      ((float)(((1.0 / 127.0) * 0.04) / 0.03))        // PROB*V_OUT/OUT_IN

__device__ __forceinline__ float bf2f(short u){
  union { float f; unsigned int i; } t;
  t.i = ((unsigned int)(unsigned short)u) << 16;
  return t.f;
}
__device__ __forceinline__ short f2bf(float f){
  union { float f; unsigned int i; } t; t.f = f;
  unsigned int r = t.i + 0x7fffu + ((t.i >> 16) & 1u);
  return (short)(r >> 16);
}
__device__ __forceinline__ float clip127(float r){
  return fminf(fmaxf(r, -127.0f), 127.0f);
}

// ---------------- prep: fp32 -> bf16 (optionally with /0.02 quantize) ----------
template<bool QUANT>
__global__ void cvt_kernel(const float* __restrict__ src, short* __restrict__ dst, int n){
  int i = (blockIdx.x * blockDim.x + threadIdx.x) * 4;
  if (i >= n) return;
  float4 v = *(const float4*)(src + i);
  float x[4] = {v.x, v.y, v.z, v.w};
  short4v o;
#pragma unroll
  for (int j = 0; j < 4; ++j){
    float t = x[j];
    if (QUANT) t = clip127(rintf(t / 0.02f));   // _q8(h / ATTN_IN_SCALE)
    o[j] = f2bf(t);
  }
  *(short4v*)(dst + i) = o;
}

// ---------------- GEMM: Y = A(MxK) * Bt(NxK)^T, bf16 in, int-exact fp32 acc ----
// MODE 0: Y(bf16) = clip(rint(acc*0.002 + bias[col]))   (QKV projections)
// MODE 1: Y(f32)  = acc*0.001 + bias[col]               (output projection)
template<int MODE>
__global__ __launch_bounds__(256)
void gemm_bt(const short* __restrict__ A, const short* __restrict__ Bt,
             const float* __restrict__ bias, void* __restrict__ Y){
#pragma clang fp contract(off)
  constexpr int Kd = 2048, N = 2048;
  __shared__ __attribute__((aligned(16))) short As[128*32];
  __shared__ __attribute__((aligned(16))) short Bs[128*32];
  const int bm = blockIdx.x, bn = blockIdx.y;
  const int tid = threadIdx.x;
  const int wid = tid >> 6, lane = tid & 63;
  const int wm = wid >> 1, wn = wid & 1;          // 2x2 waves -> 64x64 subtiles
  const int col16 = lane & 15, g = lane >> 4;
  f32x4 acc[4][4] = {};
  const short* Ab = A + (size_t)(bm*128)*Kd;
  const short* Bb = Bt + (size_t)(bn*128)*Kd;
  for (int kt = 0; kt < Kd/32; ++kt){
#pragma unroll
    for (int i = 0; i < 2; ++i){
      int v = i*256 + tid;
      int row = v >> 2, col = (v & 3) * 8;
      *(bf16x8*)&As[row*32 + col] = *(const bf16x8*)&Ab[(size_t)row*Kd + kt*32 + col];
      *(bf16x8*)&Bs[row*32 + col] = *(const bf16x8*)&Bb[(size_t)row*Kd + kt*32 + col];
    }
    __syncthreads();
    bf16x8 af[4], bfr[4];
#pragma unroll
    for (int i = 0; i < 4; ++i)
      af[i] = *(const bf16x8*)&As[(wm*64 + i*16 + col16)*32 + g*8];
#pragma unroll
    for (int j = 0; j < 4; ++j)
      bfr[j] = *(const bf16x8*)&Bs[(wn*64 + j*16 + col16)*32 + g*8];
#pragma unroll
    for (int i = 0; i < 4; ++i)
#pragma unroll
      for (int j = 0; j < 4; ++j)
        acc[i][j] = __builtin_amdgcn_mfma_f32_16x16x32_bf16(af[i], bfr[j], acc[i][j], 0, 0, 0);
    __syncthreads();
  }
  // epilogue: C/D layout col = lane&15, row = (lane>>4)*4 + reg   [measured m89]
#pragma unroll
  for (int i = 0; i < 4; ++i){
#pragma unroll
    for (int j = 0; j < 4; ++j){
      int row0 = bm*128 + wm*64 + i*16 + g*4;
      int col  = bn*128 + wn*64 + j*16 + col16;
#pragma unroll
      for (int r = 0; r < 4; ++r){
        float a = acc[i][j][r];
        if (MODE == 0){
          float t = a * 0.002f;       // einsum * W_ALPHA
          t = t + bias[col];          // + BETA*b (BETA=1)
          t = clip127(rintf(t));
          ((short*)Y)[(size_t)(row0 + r)*N + col] = f2bf(t);
        } else {
          float t = a * 0.001f;       // einsum * O_ALPHA
          t = t + bias[col];
          ((float*)Y)[(size_t)(row0 + r)*N + col] = t;
        }
      }
    }
  }
}

// ---------------- RoPE (in place on q8 / k8, both scales 0.05 -> 0.06) --------
__global__ void rope_qk(short* __restrict__ q, short* __restrict__ k,
                        const float* __restrict__ cosp, const float* __restrict__ sinp){
#pragma clang fp contract(off)
  int idx = blockIdx.x * blockDim.x + threadIdx.x;  // S*NH*HALF threads
  int d = idx & (HALF-1);
  int h = (idx >> 6) & (NH-1);
  int s = idx >> 10;
  if (s >= S) return;
  float c = cosp[s*HALF + d], sn = sinp[s*HALF + d];
  int base = s*HID + h*HD + d;
  {
    float x0 = bf2f(q[base]) * 0.05f;
    float x1 = bf2f(q[base + HALF]) * 0.05f;
    float r0 = x0*c - x1*sn;
    float r1 = x0*sn + x1*c;
    q[base]        = f2bf(clip127(rintf(r0 / 0.06f)));
    q[base + HALF] = f2bf(clip127(rintf(r1 / 0.06f)));
  }
  {
    float x0 = bf2f(k[base]) * 0.05f;
    float x1 = bf2f(k[base + HALF]) * 0.05f;
    float r0 = x0*c - x1*sn;
    float r1 = x0*sn + x1*c;
    k[base]        = f2bf(clip127(rintf(r0 / 0.06f)));
    k[base + HALF] = f2bf(clip127(rintf(r1 / 0.06f)));
  }
}

// ---------------- V transpose: vt[h][d][s] = v[s][h*HD+d] ---------------------
__global__ void vtrans(const short* __restrict__ v, short* __restrict__ vt){
  __shared__ __attribute__((aligned(16))) short t[64][72];
  int s0 = blockIdx.x * 64, d0 = blockIdx.y * 64, h = blockIdx.z;
  int tid = threadIdx.x;
#pragma unroll
  for (int i = 0; i < 2; ++i){
    int vi = i*256 + tid;
    int r = vi >> 3, c = (vi & 7) * 8;
    *(bf16x8*)&t[r][c] = *(const bf16x8*)&v[(size_t)(s0 + r)*HID + h*HD + d0 + c];
  }
  __syncthreads();
#pragma unroll
  for (int i = 0; i < 2; ++i){
    int vi = i*256 + tid;
    int rd = vi >> 3, cs = (vi & 7) * 8;
    bf16x8 o;
#pragma unroll
    for (int j = 0; j < 8; ++j) o[j] = t[cs + j][rd];
    *(bf16x8*)&vt[(size_t)(h*HD + d0 + rd)*S + s0 + cs] = o;
  }
}

// ---------------- attention helpers ------------------------------------------
__device__ __forceinline__ void stage128(short* dst, const short* src){
  const int tid = threadIdx.x;
#pragma unroll
  for (int i = 0; i < 8; ++i){
    int v = i*256 + tid;
    int row = v >> 4, col = (v & 15) * 8;
    *(bf16x8*)&dst[row*128 + col] = *(const bf16x8*)&src[(size_t)row*2048 + col];
  }
}

__device__ __forceinline__ void compute_scores(f32x4 (&sc)[2][8], const bf16x8 (&aq)[2][4],
                                               const short* Ks, int col16, int g){
#pragma unroll
  for (int kk = 0; kk < 4; ++kk){
    bf16x8 bk[8];
#pragma unroll
    for (int j = 0; j < 8; ++j)
      bk[j] = *(const bf16x8*)&Ks[(j*16 + col16)*128 + kk*32 + g*8];
#pragma unroll
    for (int i = 0; i < 2; ++i)
#pragma unroll
      for (int j = 0; j < 8; ++j)
        sc[i][j] = __builtin_amdgcn_mfma_f32_16x16x32_bf16(aq[i][kk], bk[j], sc[i][j], 0, 0, 0);
  }
}

// ---------------- fused causal attention (one block per (q-tile, head)) -------
__global__ __launch_bounds__(256, 1)
void attn(const short* __restrict__ qr, const short* __restrict__ kr,
          const short* __restrict__ vt, short* __restrict__ o8){
  const int qt = blockIdx.x, h = blockIdx.y;
  const int q0 = qt * 128;
  const int tid = threadIdx.x, wid = tid >> 6, lane = tid & 63;
  const int col16 = lane & 15, g = lane >> 4;
  __shared__ __attribute__((aligned(16))) short Ks[128*128];   // [k][d]
  __shared__ __attribute__((aligned(16))) short Vs[128*128];   // [d][k]
  __shared__ __attribute__((aligned(16))) short Ps[4][32*128]; // per-wave [q][k]

  // Q fragments in registers: wave handles rows q0+wid*32 .. +31
  bf16x8 aq[2][4];
#pragma unroll
  for (int i = 0; i < 2; ++i)
#pragma unroll
    for (int kk = 0; kk < 4; ++kk){
      int row = q0 + wid*32 + i*16 + col16;
      aq[i][kk] = *(const bf16x8*)&qr[(size_t)row*HID + h*HD + kk*32 + g*8];
    }

  float m[8], l[8];
#pragma unroll
  for (int t = 0; t < 8; ++t){ m[t] = -INFINITY; l[t] = 0.0f; }

  const int ntiles = qt + 1;

  // ---- pass 1: row max + exp-sum (online) ----
  for (int kt = 0; kt < ntiles; ++kt){
    stage128(Ks, kr + (size_t)(kt*128)*HID + h*HD);
    __syncthreads();
    f32x4 sc[2][8] = {};
    compute_scores(sc, aq, Ks, col16, g);
#pragma unroll
    for (int i = 0; i < 2; ++i){
#pragma unroll
      for (int r = 0; r < 4; ++r){
        int idx = i*4 + r;
        int qrow = q0 + wid*32 + i*16 + g*4 + r;
        float vals[8]; float mt = -1e30f;
#pragma unroll
        for (int j = 0; j < 8; ++j){
          float sv = sc[i][j][r] * SCORE_SCALE;
          int kcol = kt*128 + j*16 + col16;
          if (kcol > qrow) sv = -1e9f;
          vals[j] = sv;
          mt = fmaxf(mt, sv);
        }
        mt = fmaxf(mt, __shfl_xor(mt, 1));
        mt = fmaxf(mt, __shfl_xor(mt, 2));
        mt = fmaxf(mt, __shfl_xor(mt, 4));
        mt = fmaxf(mt, __shfl_xor(mt, 8));
        float mnew = fmaxf(m[idx], mt);
        float sum = 0.f;
#pragma unroll
        for (int j = 0; j < 8; ++j) sum += expf(vals[j] - mnew);
        sum += __shfl_xor(sum, 1);
        sum += __shfl_xor(sum, 2);
        sum += __shfl_xor(sum, 4);
        sum += __shfl_xor(sum, 8);
        l[idx] = l[idx] * expf(m[idx] - mnew) + sum;
        m[idx] = mnew;
      }
    }
    __syncthreads();
  }

  // ---- pass 2: p8 = rint(127*exp(s-m)/l) -> LDS -> PV MFMA ----
  f32x4 ao[2][8] = {};
  for (int kt = 0; kt < ntiles; ++kt){
    stage128(Ks, kr + (size_t)(kt*128)*HID + h*HD);
    stage128(Vs, vt + (size_t)(h*HD)*S + kt*128);
    __syncthreads();
    f32x4 sc[2][8] = {};
    compute_scores(sc, aq, Ks, col16, g);
#pragma unroll
    for (int i = 0; i < 2; ++i){
#pragma unroll
      for (int r = 0; r < 4; ++r){
        int idx = i*4 + r;
        int qrow = q0 + wid*32 + i*16 + g*4 + r;
#pragma unroll
        for (int j = 0; j < 8; ++j){
          int kcol = kt*128 + j*16 + col16;
          float p8v = 0.0f;
          if (kcol <= qrow){
            float sv = sc[i][j][r] * SCORE_SCALE;
            float p = expf(sv - m[idx]) / l[idx];   // softmax then *127, as reference
            p8v = clip127(rintf(p * 127.0f));
          }
          Ps[wid][(i*16 + g*4 + r)*128 + j*16 + col16] = f2bf(p8v);
        }
      }
    }
    // wave-private Ps: ds_write->ds_read dependency handled by compiler waitcnt
#pragma unroll
    for (int kk = 0; kk < 4; ++kk){
      bf16x8 ap[2], bv[8];
#pragma unroll
      for (int i = 0; i < 2; ++i)
        ap[i] = *(const bf16x8*)&Ps[wid][(i*16 + col16)*128 + kk*32 + g*8];
#pragma unroll
      for (int j = 0; j < 8; ++j)
        bv[j] = *(const bf16x8*)&Vs[(j*16 + col16)*128 + kk*32 + g*8];
#pragma unroll
      for (int i = 0; i < 2; ++i)
#pragma unroll
        for (int j = 0; j < 8; ++j)
          ao[i][j] = __builtin_amdgcn_mfma_f32_16x16x32_bf16(ap[i], bv[j], ao[i][j], 0, 0, 0);
    }
    __syncthreads();
  }

  // epilogue: o8 = clip(rint(acc * OSCALE)), store bf16 at [s][h*HD+d]
#pragma unroll
  for (int i = 0; i < 2; ++i)
#pragma unroll
    for (int j = 0; j < 8; ++j)
#pragma unroll
      for (int r = 0; r < 4; ++r){
        int row = q0 + wid*32 + i*16 + g*4 + r;
        int d = j*16 + col16;
        float t = clip127(rintf(ao[i][j][r] * OSCALE));
        o8[(size_t)row*HID + h*HD + d] = f2bf(t);
      }
}

// ---------------- launch -------------------------------------------------------
extern "C" void kernel_launch(void* const* d_in, const int* in_sizes, int n_in,
                              void* d_out, int out_size, void* d_ws, size_t ws_size,
                              hipStream_t stream) {
  const float* hidden = (const float*)d_in[0];
  const float* cosp   = (const float*)d_in[1];
  const float* sinp   = (const float*)d_in[2];
  const float* wq     = (const float*)d_in[3];
  const float* wk     = (const float*)d_in[4];
  const float* wv     = (const float*)d_in[5];
  const float* wo     = (const float*)d_in[6];
  const float* bq     = (const float*)d_in[7];
  const float* bk     = (const float*)d_in[8];
  const float* bv     = (const float*)d_in[9];
  const float* bo     = (const float*)d_in[10];
  float* out = (float*)d_out;

  const size_t MAT = (size_t)HID * HID; // 4.19M elements
  short* ws  = (short*)d_ws;
  short* xbf = ws;            // x8 (bf16); reused as o8 after QKV GEMMs complete
  short* wqb = ws + 1*MAT;
  short* wkb = ws + 2*MAT;
  short* wvb = ws + 3*MAT;
  short* wob = ws + 4*MAT;
  short* qb  = ws + 5*MAT;    // q8 -> q_rot (in place)
  short* kb  = ws + 6*MAT;    // k8 -> k_rot (in place)
  short* vb  = ws + 7*MAT;    // v8
  short* vtb = ws + 8*MAT;    // v8 transposed per head: [h][d][s]
  short* o8b = xbf;

  const int n = (int)MAT;
  dim3 b256(256);

  cvt_kernel<true ><<<n/1024, b256, 0, stream>>>(hidden, xbf, n);
  cvt_kernel<false><<<n/1024, b256, 0, stream>>>(wq, wqb, n);
  cvt_kernel<false><<<n/1024, b256, 0, stream>>>(wk, wkb, n);
  cvt_kernel<false><<<n/1024, b256, 0, stream>>>(wv, wvb, n);
  cvt_kernel<false><<<n/1024, b256, 0, stream>>>(wo, wob, n);

  dim3 gg(16, 16);
  gemm_bt<0><<<gg, b256, 0, stream>>>(xbf, wqb, bq, qb);
  gemm_bt<0><<<gg, b256, 0, stream>>>(xbf, wkb, bk, kb);
  gemm_bt<0><<<gg, b256, 0, stream>>>(xbf, wvb, bv, vb);

  rope_qk<<<(S*NH*HALF)/256, b256, 0, stream>>>(qb, kb, cosp, sinp);
  vtrans<<<dim3(S/64, HD/64, NH), b256, 0, stream>>>(vb, vtb);

  attn<<<dim3(S/128, NH), b256, 0, stream>>>(qb, kb, vtb, o8b);

  gemm_bt<1><<<gg, b256, 0, stream>>>(o8b, wob, bo, (void*)out);
}

// Round 2
// 402.644 us; speedup vs baseline: 1.2902x; 1.2902x over previous
//
#include <hip/hip_runtime.h>
#include <math.h>

typedef __attribute__((ext_vector_type(8))) short bf16x8;
typedef __attribute__((ext_vector_type(4))) short short4v;
typedef __attribute__((ext_vector_type(4))) float f32x4;

constexpr int S   = 2048;
constexpr int HID = 2048;
constexpr int NH  = 16;
constexpr int HD  = 128;
constexpr int HALF = 64;

#define SCORE_SCALE ((float)(0.06 * 0.06 * 0.08838834764831845))   // Q_ROT*K_ROT*INV_SQRT_HD
#define OSCALE      ((float)(((1.0 / 127.0) * 0.04) / 0.03))        // PROB*V_OUT/OUT_IN

__device__ __forceinline__ float bf2f(short u){
  union { float f; unsigned int i; } t;
  t.i = ((unsigned int)(unsigned short)u) << 16;
  return t.f;
}
__device__ __forceinline__ short f2bf(float f){
  union { float f; unsigned int i; } t; t.f = f;
  unsigned int r = t.i + 0x7fffu + ((t.i >> 16) & 1u);
  return (short)(r >> 16);
}
__device__ __forceinline__ float clip127(float r){
  return fminf(fmaxf(r, -127.0f), 127.0f);
}

// ---------------- prep: fp32 -> bf16 (optionally with /0.02 quantize) ----------
template<bool QUANT>
__global__ void cvt_kernel(const float* __restrict__ src, short* __restrict__ dst, int n){
  int i = (blockIdx.x * blockDim.x + threadIdx.x) * 4;
  if (i >= n) return;
  float4 v = *(const float4*)(src + i);
  float x[4] = {v.x, v.y, v.z, v.w};
  short4v o;
#pragma unroll
  for (int j = 0; j < 4; ++j){
    float t = x[j];
    if (QUANT) t = clip127(rintf(t / 0.02f));
    o[j] = f2bf(t);
  }
  *(short4v*)(dst + i) = o;
}

// ---------------- GEMM: Y = A(MxK) * Bt(NxK)^T ---------------------------------
// MODE 0: Y(bf16) = clip(rint(acc*0.002 + bias[col]))   (QKV projections)
// MODE 1: Y(f32)  = acc*0.001 + bias[col]               (output projection)
template<int MODE>
__global__ __launch_bounds__(256)
void gemm_bt(const short* __restrict__ A, const short* __restrict__ Bt,
             const float* __restrict__ bias, void* __restrict__ Y){
#pragma clang fp contract(off)
  constexpr int Kd = 2048, N = 2048;
  __shared__ __attribute__((aligned(16))) short As[128*32];
  __shared__ __attribute__((aligned(16))) short Bs[128*32];
  const int bm = blockIdx.x, bn = blockIdx.y;
  const int tid = threadIdx.x;
  const int wid = tid >> 6, lane = tid & 63;
  const int wm = wid >> 1, wn = wid & 1;
  const int col16 = lane & 15, g = lane >> 4;
  f32x4 acc[4][4] = {};
  const short* Ab = A + (size_t)(bm*128)*Kd;
  const short* Bb = Bt + (size_t)(bn*128)*Kd;
  for (int kt = 0; kt < Kd/32; ++kt){
#pragma unroll
    for (int i = 0; i < 2; ++i){
      int v = i*256 + tid;
      int row = v >> 2, cw = v & 3;
      int sw = (cw ^ ((row>>1)&3)) * 16;      // 2-bit XOR swizzle: 8-way -> 2-way
      *(bf16x8*)((char*)As + row*64 + sw) = *(const bf16x8*)&Ab[(size_t)row*Kd + kt*32 + cw*8];
      *(bf16x8*)((char*)Bs + row*64 + sw) = *(const bf16x8*)&Bb[(size_t)row*Kd + kt*32 + cw*8];
    }
    __syncthreads();
    bf16x8 af[4], bfr[4];
#pragma unroll
    for (int i = 0; i < 4; ++i){
      int row = wm*64 + i*16 + col16;
      af[i] = *(const bf16x8*)((const char*)As + row*64 + ((g ^ ((row>>1)&3))*16));
    }
#pragma unroll
    for (int j = 0; j < 4; ++j){
      int row = wn*64 + j*16 + col16;
      bfr[j] = *(const bf16x8*)((const char*)Bs + row*64 + ((g ^ ((row>>1)&3))*16));
    }
#pragma unroll
    for (int i = 0; i < 4; ++i)
#pragma unroll
      for (int j = 0; j < 4; ++j)
        acc[i][j] = __builtin_amdgcn_mfma_f32_16x16x32_bf16(af[i], bfr[j], acc[i][j], 0, 0, 0);
    __syncthreads();
  }
#pragma unroll
  for (int i = 0; i < 4; ++i){
#pragma unroll
    for (int j = 0; j < 4; ++j){
      int row0 = bm*128 + wm*64 + i*16 + g*4;
      int col  = bn*128 + wn*64 + j*16 + col16;
#pragma unroll
      for (int r = 0; r < 4; ++r){
        float a = acc[i][j][r];
        if (MODE == 0){
          float t = a * 0.002f;
          t = t + bias[col];
          t = clip127(rintf(t));
          ((short*)Y)[(size_t)(row0 + r)*N + col] = f2bf(t);
        } else {
          float t = a * 0.001f;
          t = t + bias[col];
          ((float*)Y)[(size_t)(row0 + r)*N + col] = t;
        }
      }
    }
  }
}

// ---------------- RoPE (in place on q8 / k8) ----------------------------------
__global__ void rope_qk(short* __restrict__ q, short* __restrict__ k,
                        const float* __restrict__ cosp, const float* __restrict__ sinp){
#pragma clang fp contract(off)
  int idx = blockIdx.x * blockDim.x + threadIdx.x;
  int d = idx & (HALF-1);
  int h = (idx >> 6) & (NH-1);
  int s = idx >> 10;
  if (s >= S) return;
  float c = cosp[s*HALF + d], sn = sinp[s*HALF + d];
  int base = s*HID + h*HD + d;
  {
    float x0 = bf2f(q[base]) * 0.05f;
    float x1 = bf2f(q[base + HALF]) * 0.05f;
    float r0 = x0*c - x1*sn;
    float r1 = x0*sn + x1*c;
    q[base]        = f2bf(clip127(rintf(r0 / 0.06f)));
    q[base + HALF] = f2bf(clip127(rintf(r1 / 0.06f)));
  }
  {
    float x0 = bf2f(k[base]) * 0.05f;
    float x1 = bf2f(k[base + HALF]) * 0.05f;
    float r0 = x0*c - x1*sn;
    float r1 = x0*sn + x1*c;
    k[base]        = f2bf(clip127(rintf(r0 / 0.06f)));
    k[base + HALF] = f2bf(clip127(rintf(r1 / 0.06f)));
  }
}

// ---------------- V transpose: vt[h][d][s] = v[s][h*HD+d] ---------------------
__global__ void vtrans(const short* __restrict__ v, short* __restrict__ vt){
  __shared__ __attribute__((aligned(16))) short t[64][72];
  int s0 = blockIdx.x * 64, d0 = blockIdx.y * 64, h = blockIdx.z;
  int tid = threadIdx.x;
#pragma unroll
  for (int i = 0; i < 2; ++i){
    int vi = i*256 + tid;
    int r = vi >> 3, c = (vi & 7) * 8;
    *(bf16x8*)&t[r][c] = *(const bf16x8*)&v[(size_t)(s0 + r)*HID + h*HD + d0 + c];
  }
  __syncthreads();
#pragma unroll
  for (int i = 0; i < 2; ++i){
    int vi = i*256 + tid;
    int rd = vi >> 3, cs = (vi & 7) * 8;
    bf16x8 o;
#pragma unroll
    for (int j = 0; j < 8; ++j) o[j] = t[cs + j][rd];
    *(bf16x8*)&vt[(size_t)(h*HD + d0 + rd)*S + s0 + cs] = o;
  }
}

// ---------------- swizzled 128x128 bf16 LDS staging ---------------------------
// byte_off = row*256 + ((chunk ^ (row&7))*16): conflict-free writes AND reads
__device__ __forceinline__ void stage_swz(short* dst, const short* src){
  const int tid = threadIdx.x;
#pragma unroll
  for (int i = 0; i < 8; ++i){
    int v = i*256 + tid;
    int row = v >> 4, chunk = v & 15;
    bf16x8 val = *(const bf16x8*)&src[(size_t)row*2048 + chunk*8];
    *(bf16x8*)((char*)dst + row*256 + ((chunk ^ (row & 7))*16)) = val;
  }
}
__device__ __forceinline__ bf16x8 rdfrag(const short* buf, int row, int chunk){
  return *(const bf16x8*)((const char*)buf + row*256 + ((chunk ^ (row & 7))*16));
}

// ---------------- S: per-(head, qt, kt) tile stats (balanced grid) -------------
__global__ __launch_bounds__(256)
void attn_stats(const short* __restrict__ qr, const short* __restrict__ kr,
                float2* __restrict__ stats){
  const int x = blockIdx.x, h = blockIdx.y;
  int qt = (int)((sqrtf(8.f*x + 1.f) - 1.f)*0.5f);
  while ((qt+1)*(qt+2)/2 <= x) ++qt;
  while (qt*(qt+1)/2 > x) --qt;
  const int kt = x - qt*(qt+1)/2;
  const int q0 = qt*128;
  const int tid = threadIdx.x, wid = tid >> 6, lane = tid & 63;
  const int col16 = lane & 15, g = lane >> 4;
  __shared__ __attribute__((aligned(16))) short Ks[128*128];

  bf16x8 aq[2][4];
#pragma unroll
  for (int i = 0; i < 2; ++i)
#pragma unroll
    for (int kk = 0; kk < 4; ++kk){
      int row = q0 + wid*32 + i*16 + col16;
      aq[i][kk] = *(const bf16x8*)&qr[(size_t)row*HID + h*HD + kk*32 + g*8];
    }
  stage_swz(Ks, kr + (size_t)(kt*128)*HID + h*HD);
  __syncthreads();

  f32x4 sc[2][8] = {};
#pragma unroll
  for (int kk = 0; kk < 4; ++kk){
    bf16x8 bk[8];
#pragma unroll
    for (int j = 0; j < 8; ++j) bk[j] = rdfrag(Ks, j*16 + col16, kk*4 + g);
#pragma unroll
    for (int i = 0; i < 2; ++i)
#pragma unroll
      for (int j = 0; j < 8; ++j)
        sc[i][j] = __builtin_amdgcn_mfma_f32_16x16x32_bf16(aq[i][kk], bk[j], sc[i][j], 0, 0, 0);
  }

  const bool diag = (kt == qt);
#pragma unroll
  for (int i = 0; i < 2; ++i){
#pragma unroll
    for (int r = 0; r < 4; ++r){
      int rit = wid*32 + i*16 + g*4 + r;
      int qrow = q0 + rit;
      float vals[8]; float mt = -3.0e38f;
#pragma unroll
      for (int j = 0; j < 8; ++j){
        float sv = sc[i][j][r] * SCORE_SCALE;
        if (diag && (kt*128 + j*16 + col16 > qrow)) sv = -1e9f;
        vals[j] = sv;
        mt = fmaxf(mt, sv);
      }
      mt = fmaxf(mt, __shfl_xor(mt, 1));
      mt = fmaxf(mt, __shfl_xor(mt, 2));
      mt = fmaxf(mt, __shfl_xor(mt, 4));
      mt = fmaxf(mt, __shfl_xor(mt, 8));
      float st = 0.f;
#pragma unroll
      for (int j = 0; j < 8; ++j) st += __expf(vals[j] - mt);
      st += __shfl_xor(st, 1);
      st += __shfl_xor(st, 2);
      st += __shfl_xor(st, 4);
      st += __shfl_xor(st, 8);
      if (col16 == 0) stats[(size_t)(h*136 + x)*128 + rit] = make_float2(mt, st);
    }
  }
}

// ---------------- R: combine tile stats -> final (m, l) per row ---------------
__global__ void attn_reduce(const float2* __restrict__ stats, float2* __restrict__ ml){
  const int row = threadIdx.x, qt = blockIdx.x, h = blockIdx.y;
  const int tri = qt*(qt+1)/2;
  float m = -3.0e38f;
  for (int kt = 0; kt <= qt; ++kt)
    m = fmaxf(m, stats[(size_t)(h*136 + tri + kt)*128 + row].x);
  float l = 0.f;
  for (int kt = 0; kt <= qt; ++kt){
    float2 s = stats[(size_t)(h*136 + tri + kt)*128 + row];
    l += s.y * __expf(s.x - m);
  }
  ml[(h*16 + qt)*128 + row] = make_float2(m, l);
}

// ---------------- P: single-pass PV with final (m,l) --------------------------
__global__ __launch_bounds__(256, 2)
void attn_pv(const short* __restrict__ qr, const short* __restrict__ kr,
             const short* __restrict__ vt, const float2* __restrict__ ml,
             short* __restrict__ o8){
  const int qt = blockIdx.x, h = blockIdx.y;
  const int q0 = qt*128;
  const int tid = threadIdx.x, wid = tid >> 6, lane = tid & 63;
  const int col16 = lane & 15, g = lane >> 4;
  __shared__ __attribute__((aligned(16))) short KV[128*128];   // K then V (swizzled)
  __shared__ __attribute__((aligned(16))) short Ps[4][32*136]; // padded: 272B stride

  bf16x8 aq[2][4];
#pragma unroll
  for (int i = 0; i < 2; ++i)
#pragma unroll
    for (int kk = 0; kk < 4; ++kk){
      int row = q0 + wid*32 + i*16 + col16;
      aq[i][kk] = *(const bf16x8*)&qr[(size_t)row*HID + h*HD + kk*32 + g*8];
    }
  float m[8], c[8];
#pragma unroll
  for (int i = 0; i < 2; ++i)
#pragma unroll
    for (int r = 0; r < 4; ++r){
      float2 t = ml[(h*16 + qt)*128 + wid*32 + i*16 + g*4 + r];
      m[i*4+r] = t.x;
      c[i*4+r] = 127.0f / t.y;
    }

  f32x4 ao[2][8] = {};
  for (int kt = 0; kt <= qt; ++kt){
    stage_swz(KV, kr + (size_t)(kt*128)*HID + h*HD);
    __syncthreads();
    f32x4 sc[2][8] = {};
#pragma unroll
    for (int kk = 0; kk < 4; ++kk){
      bf16x8 bk[8];
#pragma unroll
      for (int j = 0; j < 8; ++j) bk[j] = rdfrag(KV, j*16 + col16, kk*4 + g);
#pragma unroll
      for (int i = 0; i < 2; ++i)
#pragma unroll
        for (int j = 0; j < 8; ++j)
          sc[i][j] = __builtin_amdgcn_mfma_f32_16x16x32_bf16(aq[i][kk], bk[j], sc[i][j], 0, 0, 0);
    }
    __syncthreads();            // K consumed
    stage_swz(KV, vt + (size_t)(h*HD)*S + kt*128);   // V staging overlaps p8 VALU
    const bool diag = (kt == qt);
#pragma unroll
    for (int i = 0; i < 2; ++i){
#pragma unroll
      for (int r = 0; r < 4; ++r){
        int idx = i*4 + r;
        int qrow = q0 + wid*32 + i*16 + g*4 + r;
#pragma unroll
        for (int j = 0; j < 8; ++j){
          int kcol = kt*128 + j*16 + col16;
          float p8v = 0.0f;
          if (!diag || kcol <= qrow){
            float sv = sc[i][j][r] * SCORE_SCALE;
            p8v = clip127(rintf(__expf(sv - m[idx]) * c[idx]));
          }
          Ps[wid][(i*16 + g*4 + r)*136 + j*16 + col16] = f2bf(p8v);
        }
      }
    }
    __syncthreads();            // V ready (Ps is wave-private)
#pragma unroll
    for (int kk = 0; kk < 4; ++kk){
      bf16x8 ap[2], bv[8];
#pragma unroll
      for (int i = 0; i < 2; ++i)
        ap[i] = *(const bf16x8*)&Ps[wid][(i*16 + col16)*136 + kk*32 + g*8];
#pragma unroll
      for (int j = 0; j < 8; ++j)
        bv[j] = rdfrag(KV, j*16 + col16, kk*4 + g);
#pragma unroll
      for (int i = 0; i < 2; ++i)
#pragma unroll
        for (int j = 0; j < 8; ++j)
          ao[i][j] = __builtin_amdgcn_mfma_f32_16x16x32_bf16(ap[i], bv[j], ao[i][j], 0, 0, 0);
    }
    __syncthreads();            // V consumed
  }

#pragma unroll
  for (int i = 0; i < 2; ++i)
#pragma unroll
    for (int j = 0; j < 8; ++j)
#pragma unroll
      for (int r = 0; r < 4; ++r){
        int row = q0 + wid*32 + i*16 + g*4 + r;
        int d = j*16 + col16;
        float t = clip127(rintf(ao[i][j][r] * OSCALE));
        o8[(size_t)row*HID + h*HD + d] = f2bf(t);
      }
}

// ---------------- launch -------------------------------------------------------
extern "C" void kernel_launch(void* const* d_in, const int* in_sizes, int n_in,
                              void* d_out, int out_size, void* d_ws, size_t ws_size,
                              hipStream_t stream) {
  const float* hidden = (const float*)d_in[0];
  const float* cosp   = (const float*)d_in[1];
  const float* sinp   = (const float*)d_in[2];
  const float* wq     = (const float*)d_in[3];
  const float* wk     = (const float*)d_in[4];
  const float* wv     = (const float*)d_in[5];
  const float* wo     = (const float*)d_in[6];
  const float* bq     = (const float*)d_in[7];
  const float* bk     = (const float*)d_in[8];
  const float* bv     = (const float*)d_in[9];
  const float* bo     = (const float*)d_in[10];
  float* out = (float*)d_out;

  const size_t MAT = (size_t)HID * HID;
  short* ws  = (short*)d_ws;
  short* xbf = ws;            // x8; reused as o8 after QKV GEMMs complete
  short* wqb = ws + 1*MAT;
  short* wkb = ws + 2*MAT;
  short* wvb = ws + 3*MAT;
  short* wob = ws + 4*MAT;
  short* qb  = ws + 5*MAT;
  short* kb  = ws + 6*MAT;
  short* vb  = ws + 7*MAT;
  short* vtb = ws + 8*MAT;
  short* o8b = xbf;
  // reuse dead weight-conversion slots after QKV GEMMs:
  float2* stats = (float2*)wqb;   // 16*136*128*8B = 2.23 MB  (< 8.39 MB slot)
  float2* mlb   = (float2*)wkb;   // 16*2048*8B   = 0.26 MB

  const int n = (int)MAT;
  dim3 b256(256);

  cvt_kernel<true ><<<n/1024, b256, 0, stream>>>(hidden, xbf, n);
  cvt_kernel<false><<<n/1024, b256, 0, stream>>>(wq, wqb, n);
  cvt_kernel<false><<<n/1024, b256, 0, stream>>>(wk, wkb, n);
  cvt_kernel<false><<<n/1024, b256, 0, stream>>>(wv, wvb, n);
  cvt_kernel<false><<<n/1024, b256, 0, stream>>>(wo, wob, n);

  dim3 gg(16, 16);
  gemm_bt<0><<<gg, b256, 0, stream>>>(xbf, wqb, bq, qb);
  gemm_bt<0><<<gg, b256, 0, stream>>>(xbf, wkb, bk, kb);
  gemm_bt<0><<<gg, b256, 0, stream>>>(xbf, wvb, bv, vb);

  rope_qk<<<(S*NH*HALF)/256, b256, 0, stream>>>(qb, kb, cosp, sinp);
  vtrans<<<dim3(S/64, HD/64, NH), b256, 0, stream>>>(vb, vtb);

  attn_stats<<<dim3(136, 16), b256, 0, stream>>>(qb, kb, stats);
  attn_reduce<<<dim3(16, 16), dim3(128), 0, stream>>>(stats, mlb);
  attn_pv<<<dim3(16, 16), b256, 0, stream>>>(qb, kb, vtb, mlb, o8b);

  gemm_bt<1><<<gg, b256, 0, stream>>>(o8b, wob, bo, (void*)out);
}